// Round 7
// baseline (154.015 us; speedup 1.0000x reference)
//
#include <hip/hip_runtime.h>
#include <hip/hip_bf16.h>
#include <math.h>

namespace {
constexpr int V = 50000, E = 256, H = 512, S = 500, B = 64, OOVN = 50;
constexpr int VEXT = V + OOVN;   // 50050
constexpr int CCAT = E + 3 * H;  // 1792  (embed | h_new | context)
constexpr int G3 = 3 * H;        // 1536
constexpr int NLB = 391;         // logits blocks (3128 waves, 3125 active)

typedef __attribute__((ext_vector_type(8))) short short8;
typedef __attribute__((ext_vector_type(4))) float f32x4;

__device__ __forceinline__ float wsum(float v) {
#pragma unroll
  for (int off = 32; off > 0; off >>= 1) v += __shfl_xor(v, off, 64);
  return v;
}
__device__ __forceinline__ float sigmoidf(float x) { return 1.f / (1.f + __expf(-x)); }
__device__ __forceinline__ float fast_tanh(float x) {
  x = fminf(fmaxf(x, -15.f), 15.f);
  float e = __expf(2.f * x);
  return __fdividef(e - 1.f, e + 1.f);
}
__device__ __forceinline__ void smerge_s(float& m, float& l, float om, float ol) {
  float nm = fmaxf(m, om);
  if (nm == -INFINITY) { m = nm; return; }
  l = l * __expf(m - nm) + ol * __expf(om - nm);
  m = nm;
}
__device__ __forceinline__ short bf16_rn_s(float f) {
  __hip_bfloat16 h = __float2bfloat16(f);
  return __builtin_bit_cast(short, h);
}
__device__ __forceinline__ float bf16s_to_f(unsigned short u) {
  return __uint_as_float(((unsigned)u) << 16);
}
__device__ __forceinline__ void hilo8(float4 a, float4 b, short8& hi, short8& lo) {
  float f[8] = {a.x, a.y, a.z, a.w, b.x, b.y, b.z, b.w};
#pragma unroll
  for (int i = 0; i < 8; ++i) {
    unsigned u = __float_as_uint(f[i]);
    hi[i] = (short)(u >> 16);
    lo[i] = bf16_rn_s(f[i] - __uint_as_float(u & 0xffff0000u));
  }
}

// ---- MFMA core, fp32 X with in-register hi/lo split; wave does C[0:64][n0:n0+16] ----
template <int KSTEPS>
__device__ __forceinline__ void gemm_core_f32(const float* __restrict__ X, int ldx,
                                              int xk0, const float* __restrict__ W,
                                              int ldw, int wk0, int n0, f32x4 acc[4]) {
  const int l = threadIdx.x & 63;
  const int r16 = l & 15, q16 = l >> 4;
#pragma unroll
  for (int t = 0; t < 4; ++t) acc[t] = (f32x4){0.f, 0.f, 0.f, 0.f};
  const float* wp = W + (size_t)(n0 + r16) * ldw + wk0 + q16 * 8;
  const float* xp[4];
#pragma unroll
  for (int t = 0; t < 4; ++t) xp[t] = X + (size_t)(t * 16 + r16) * ldx + xk0 + q16 * 8;
#pragma unroll
  for (int ks = 0; ks < KSTEPS; ++ks) {
    const int ko = ks * 32;
    float4 w0 = *reinterpret_cast<const float4*>(wp + ko);
    float4 w1 = *reinterpret_cast<const float4*>(wp + ko + 4);
    short8 whi, wlo;
    hilo8(w0, w1, whi, wlo);
#pragma unroll
    for (int t = 0; t < 4; ++t) {
      float4 x0 = *reinterpret_cast<const float4*>(xp[t] + ko);
      float4 x1 = *reinterpret_cast<const float4*>(xp[t] + ko + 4);
      short8 ah, al;
      hilo8(x0, x1, ah, al);
      acc[t] = __builtin_amdgcn_mfma_f32_16x16x32_bf16(ah, whi, acc[t], 0, 0, 0);
      acc[t] = __builtin_amdgcn_mfma_f32_16x16x32_bf16(al, whi, acc[t], 0, 0, 0);
      acc[t] = __builtin_amdgcn_mfma_f32_16x16x32_bf16(ah, wlo, acc[t], 0, 0, 0);
    }
  }
}
template <int KSTEPS>
__device__ __forceinline__ void gemm_store_f32(const float* X, int ldx, int xk0,
                                               const float* W, int ldw, int wk0, int n0,
                                               float* C, int ldc) {
  f32x4 acc[4];
  gemm_core_f32<KSTEPS>(X, ldx, xk0, W, ldw, wk0, n0, acc);
  const int l = threadIdx.x & 63;
  const int r16 = l & 15, q16 = l >> 4;
#pragma unroll
  for (int t = 0; t < 4; ++t)
#pragma unroll
    for (int r = 0; r < 4; ++r) {
      int row = t * 16 + q16 * 4 + r;
      C[(size_t)row * ldc + n0 + r16] = acc[t][r];
    }
}

// ---- head: q gemm (4 K-chunks) + embed gather + cc-ctx zero ----
__global__ void __launch_bounds__(256) k_head(const float* __restrict__ prevh,
                                              const float* __restrict__ Wq,
                                              const int* __restrict__ tok,
                                              const float* __restrict__ emb,
                                              float* __restrict__ qpart,
                                              float* __restrict__ cc) {
  int gw = blockIdx.x * 4 + (threadIdx.x >> 6);  // 0..143
  if (gw < 128) {
    int c = gw >> 5, nt = gw & 31;
    gemm_store_f32<4>(prevh, H, c * 128, Wq, H, c * 128, nt * 16,
                      qpart + (size_t)c * 64 * H, H);
  } else {
    int idx = (gw - 128) * 64 + (threadIdx.x & 63);  // 0..1023
    for (int i = idx; i < B * E; i += 1024) {
      int b = i >> 8, e = i & 255;
      cc[b * CCAT + e] = emb[(size_t)tok[b] * E + e];
    }
    for (int i = idx; i < B * 1024; i += 1024) {
      int b = i >> 10, col = i & 1023;
      cc[b * CCAT + 768 + col] = 0.f;
    }
  }
}

// ---- scoresT[b][s] = sum_h tanh(q+pk)*We ; wave per (s,b) ----
__global__ void k_scores(const float* __restrict__ qpart, const float* __restrict__ pk,
                         const float* __restrict__ We, float* __restrict__ scoresT) {
  int lane = threadIdx.x & 63;
  int gw = blockIdx.x * 4 + (threadIdx.x >> 6);  // 0..31999
  int s = gw >> 6, b = gw & 63;
  const float* q0 = qpart + b * H + lane * 8;
  const float* kr = pk + ((size_t)s * B + b) * H + lane * 8;
  const float* er = We + lane * 8;
  float part = 0.f;
#pragma unroll
  for (int i = 0; i < 2; ++i) {
    float4 qa = *reinterpret_cast<const float4*>(q0 + i * 4);
    float4 qb = *reinterpret_cast<const float4*>(q0 + 64 * H + i * 4);
    float4 qc = *reinterpret_cast<const float4*>(q0 + 128 * H + i * 4);
    float4 qd = *reinterpret_cast<const float4*>(q0 + 192 * H + i * 4);
    float4 kv = *reinterpret_cast<const float4*>(kr + i * 4);
    float4 ev = *reinterpret_cast<const float4*>(er + i * 4);
    part += fast_tanh(qa.x + qb.x + qc.x + qd.x + kv.x) * ev.x +
            fast_tanh(qa.y + qb.y + qc.y + qd.y + kv.y) * ev.y +
            fast_tanh(qa.z + qb.z + qc.z + qd.z + kv.z) * ev.z +
            fast_tanh(qa.w + qb.w + qc.w + qd.w + kv.w) * ev.w;
  }
  part = wsum(part);
  if (lane == 0) scoresT[b * S + s] = part;
}

// ---- ctx (+in-block softmax): cc[b][768+qd*256+t] += sum_{s in half} alpha*ench ----
__global__ void k_ctx(const float* __restrict__ scoresT, const float* __restrict__ ench,
                      float* __restrict__ cc, float* __restrict__ alphasT) {
  int x = blockIdx.x;  // 512 = 64b * 4qd * 2sh
  int b = x >> 3, qd = (x >> 1) & 3, sh = x & 1;
  int t = threadIdx.x;  // 256
  __shared__ float sa[250];
  __shared__ float rm[4], rl[4];
  int w = t >> 6, lane = t & 63;
  // softmax over scoresT[b][0:500]
  float v0 = scoresT[b * S + t];
  float v1 = (t + 256 < S) ? scoresT[b * S + t + 256] : -INFINITY;
  float m = fmaxf(v0, v1);
#pragma unroll
  for (int off = 32; off > 0; off >>= 1) m = fmaxf(m, __shfl_xor(m, off, 64));
  if (lane == 0) rm[w] = m;
  __syncthreads();
  float bm = fmaxf(fmaxf(rm[0], rm[1]), fmaxf(rm[2], rm[3]));
  float e0 = __expf(v0 - bm);
  float e1 = (t + 256 < S) ? __expf(v1 - bm) : 0.f;
  float sw = wsum(e0 + e1);
  if (lane == 0) rl[w] = sw;
  __syncthreads();
  float tot = rl[0] + rl[1] + rl[2] + rl[3];
  float a0v = e0 / tot;
  float a1v = e1 / tot;
  if (sh == 0) {
    if (t < 250) sa[t] = a0v;
  } else {
    if (t >= 250) sa[t - 250] = a0v;
    if (t + 256 < S) sa[t + 6] = a1v;
  }
  if (qd == 0) {
    if (sh == 0) alphasT[b * S + t] = a0v;
    else if (t + 256 < S) alphasT[b * S + t + 256] = a1v;
  }
  __syncthreads();
  const float* base = ench + ((size_t)(sh * 250) * B + b) * 1024 + qd * 256 + t;
  float a0 = 0.f, a1 = 0.f, a2 = 0.f, a3 = 0.f;
#pragma unroll 4
  for (int s = 0; s < 248; s += 4) {
    a0 += sa[s] * base[(size_t)s * (B * 1024)];
    a1 += sa[s + 1] * base[(size_t)(s + 1) * (B * 1024)];
    a2 += sa[s + 2] * base[(size_t)(s + 2) * (B * 1024)];
    a3 += sa[s + 3] * base[(size_t)(s + 3) * (B * 1024)];
  }
  a0 += sa[248] * base[(size_t)248 * (B * 1024)];
  a1 += sa[249] * base[(size_t)249 * (B * 1024)];
  atomicAdd(&cc[b * CCAT + 768 + qd * 256 + t], (a0 + a1) + (a2 + a3));
}

// ---- big fused gemm: gi (5 chunks) + lin embed/ctx chunks (5) + gh (2 chunks) ----
__global__ void __launch_bounds__(256) k_gemm_big(const float* __restrict__ cc,
                                                  const float* __restrict__ prevh,
                                                  const float* __restrict__ Wih,
                                                  const float* __restrict__ Whh,
                                                  const float* __restrict__ linW,
                                                  float* __restrict__ gip,
                                                  float* __restrict__ linpart,
                                                  float* __restrict__ ghp) {
  int w = blockIdx.x * 4 + (threadIdx.x >> 6);  // 0..831
  if (w < 480) {
    int c = w / 96, nt = w % 96;
    int xk0 = (c == 0) ? 0 : 768 + (c - 1) * 256;
    gemm_store_f32<8>(cc, CCAT, xk0, Wih, 1280, c * 256, nt * 16,
                      gip + (size_t)c * 64 * G3, G3);
  } else if (w < 640) {
    int w2 = w - 480;
    int c = w2 >> 5, nt = w2 & 31;
    int k0 = (c == 0) ? 0 : 768 + (c - 1) * 256;
    gemm_store_f32<8>(cc, CCAT, k0, linW, CCAT, k0, nt * 16,
                      linpart + (size_t)c * 64 * H, H);
  } else {
    int w2 = w - 640;
    int c = w2 / 96, nt = w2 % 96;
    gemm_store_f32<8>(prevh, H, c * 256, Whh, H, c * 256, nt * 16,
                      ghp + (size_t)c * 64 * G3, G3);
  }
}

// ---- GRU gates + p_gen: block per b, 512 threads ----
__global__ void k_gates(const float* __restrict__ gip, const float* __restrict__ ghp,
                        const float* __restrict__ bih, const float* __restrict__ bhh,
                        const float* __restrict__ prevh, const float* __restrict__ pgW,
                        const float* __restrict__ pgb, float* __restrict__ cc,
                        float* __restrict__ hout, float* __restrict__ pgsum) {
  int b = blockIdx.x, j = threadIdx.x;  // 64 x 512
  float ir = bih[j], iz = bih[512 + j], in_ = bih[1024 + j];
#pragma unroll
  for (int c = 0; c < 5; ++c) {
    const float* g = gip + (size_t)c * 64 * G3 + b * G3;
    ir += g[j]; iz += g[512 + j]; in_ += g[1024 + j];
  }
  float hr = bhh[j], hz = bhh[512 + j], hn = bhh[1024 + j];
#pragma unroll
  for (int c = 0; c < 2; ++c) {
    const float* g = ghp + (size_t)c * 64 * G3 + b * G3;
    hr += g[j]; hz += g[512 + j]; hn += g[1024 + j];
  }
  float r = sigmoidf(ir + hr);
  float z = sigmoidf(iz + hz);
  float n = fast_tanh(in_ + r * hn);
  float h = prevh[b * H + j];
  float hnew = (1.f - z) * n + z * h;
  hout[b * H + j] = hnew;
  cc[b * CCAT + E + j] = hnew;
  float acc = hnew * pgW[E + j];
  acc += cc[b * CCAT + 768 + j] * pgW[768 + j];
  acc += cc[b * CCAT + 1280 + j] * pgW[1280 + j];
  if (j < 256) acc += cc[b * CCAT + j] * pgW[j];
  acc = wsum(acc);
  __shared__ float sl[8];
  int w = j >> 6, lane = j & 63;
  if (lane == 0) sl[w] = acc;
  __syncthreads();
  if (j == 0) {
    float tot = pgb[0];
#pragma unroll
    for (int i = 0; i < 8; ++i) tot += sl[i];
    pgsum[b] = tot;
  }
}

// ---- lin h-part gemm (K=512) + sum 5 partials + bias -> lh bf16 ----
__global__ void __launch_bounds__(256) k_linfin(const float* __restrict__ cc,
                                                const float* __restrict__ linW,
                                                const float* __restrict__ linpart,
                                                const float* __restrict__ linb,
                                                short* __restrict__ lh) {
  int w = blockIdx.x * 4 + (threadIdx.x >> 6);  // 0..31
  f32x4 acc[4];
  gemm_core_f32<16>(cc, CCAT, 256, linW, CCAT, 256, w * 16, acc);
  const int l = threadIdx.x & 63;
  const int r16 = l & 15, q16 = l >> 4;
  int col = w * 16 + r16;
  float bv = linb[col];
#pragma unroll
  for (int t = 0; t < 4; ++t)
#pragma unroll
    for (int r = 0; r < 4; ++r) {
      int row = t * 16 + q16 * 4 + r;
      float v = acc[t][r] + bv;
#pragma unroll
      for (int c = 0; c < 5; ++c) v += linpart[(size_t)c * 64 * H + row * H + col];
      lh[row * H + col] = bf16_rn_s(v);
    }
}

// ---- logits gemm (bf16 out) + per-block online-softmax partials ----
__global__ void __launch_bounds__(512) k_gemm_logits(
    const short* __restrict__ lh, const float* __restrict__ outW,
    const float* __restrict__ outb, unsigned short* __restrict__ logitsb,
    float* __restrict__ pm, float* __restrict__ pl) {
  __shared__ __align__(16) short xs[64 * 512];
  __shared__ float pml[8][64][2];
  char* xb = reinterpret_cast<char*>(xs);
  int tid = threadIdx.x;
#pragma unroll
  for (int k = 0; k < 8; ++k) {
    int m = k * 512 + tid;
    int row = m >> 6;
    short8 v = *reinterpret_cast<const short8*>(lh + (size_t)m * 8);
    int byte = (m * 16) ^ ((row & 7) << 4);
    *reinterpret_cast<short8*>(xb + byte) = v;
  }
  __syncthreads();
  const int l = tid & 63;
  const int r16 = l & 15, q16 = l >> 4;
  const int wid = tid >> 6;
  const int waveId = blockIdx.x * 8 + wid;
  const bool active = waveId < V / 16;
  if (active) {
    const int n0 = waveId * 16;
    f32x4 acc[4];
#pragma unroll
    for (int t = 0; t < 4; ++t) acc[t] = (f32x4){0.f, 0.f, 0.f, 0.f};
    const float* wp = outW + (size_t)(n0 + r16) * H + q16 * 8;
    int arow[4], aswz[4];
#pragma unroll
    for (int t = 0; t < 4; ++t) {
      int row = t * 16 + r16;
      arow[t] = row * 1024 + q16 * 16;
      aswz[t] = (row & 7) << 4;
    }
#pragma unroll
    for (int ks = 0; ks < 16; ++ks) {
      float4 w0 = *reinterpret_cast<const float4*>(wp + ks * 32);
      float4 w1 = *reinterpret_cast<const float4*>(wp + ks * 32 + 4);
      short8 wh;
      wh[0] = bf16_rn_s(w0.x); wh[1] = bf16_rn_s(w0.y);
      wh[2] = bf16_rn_s(w0.z); wh[3] = bf16_rn_s(w0.w);
      wh[4] = bf16_rn_s(w1.x); wh[5] = bf16_rn_s(w1.y);
      wh[6] = bf16_rn_s(w1.z); wh[7] = bf16_rn_s(w1.w);
#pragma unroll
      for (int t = 0; t < 4; ++t) {
        short8 a = *reinterpret_cast<const short8*>(xb + ((arow[t] + ks * 64) ^ aswz[t]));
        acc[t] = __builtin_amdgcn_mfma_f32_16x16x32_bf16(a, wh, acc[t], 0, 0, 0);
      }
    }
    float bv = outb[n0 + r16];
#pragma unroll
    for (int t = 0; t < 4; ++t)
#pragma unroll
      for (int r = 0; r < 4; ++r) {
        float y = acc[t][r] + bv;
        int row = t * 16 + q16 * 4 + r;
        logitsb[(size_t)row * V + n0 + r16] = (unsigned short)bf16_rn_s(y);
        float m = y;
#pragma unroll
        for (int off = 8; off > 0; off >>= 1) m = fmaxf(m, __shfl_xor(m, off, 64));
        float e = __expf(y - m);
#pragma unroll
        for (int off = 8; off > 0; off >>= 1) e += __shfl_xor(e, off, 64);
        if (r16 == 0) { pml[wid][row][0] = m; pml[wid][row][1] = e; }
      }
  } else if (r16 == 0) {
#pragma unroll
    for (int t = 0; t < 4; ++t)
#pragma unroll
      for (int r = 0; r < 4; ++r) {
        int row = t * 16 + q16 * 4 + r;
        pml[wid][row][0] = -INFINITY;
        pml[wid][row][1] = 0.f;
      }
  }
  __syncthreads();
  if (tid < 64) {
    float m = pml[0][tid][0], lv = pml[0][tid][1];
#pragma unroll
    for (int i = 1; i < 8; ++i) smerge_s(m, lv, pml[i][tid][0], pml[i][tid][1]);
    pm[blockIdx.x * 64 + tid] = m;
    pl[blockIdx.x * 64 + tid] = lv;
  }
}

// ---- final: reduce partials -> probs in LDS -> scatter (LDS atomics) -> log -> out ----
__global__ void k_final(const unsigned short* __restrict__ logitsb,
                        const float* __restrict__ pm, const float* __restrict__ pl,
                        const float* __restrict__ pgsum, const int* __restrict__ extv,
                        const float* __restrict__ alphasT, float* __restrict__ out) {
  int b = blockIdx.x, c = blockIdx.y, t = threadIdx.x;  // 64 x 10, 256 thr
  __shared__ float sp_[5056];
  __shared__ float rm[4], rl[4];
  float m = -INFINITY, lv = 0.f;
  for (int i = t; i < NLB; i += 256) smerge_s(m, lv, pm[i * 64 + b], pl[i * 64 + b]);
#pragma unroll
  for (int off = 32; off > 0; off >>= 1) {
    float om = __shfl_xor(m, off, 64), ol = __shfl_xor(lv, off, 64);
    smerge_s(m, lv, om, ol);
  }
  int w = t >> 6, lane = t & 63;
  if (lane == 0) { rm[w] = m; rl[w] = lv; }
  __syncthreads();
  m = rm[0]; lv = rl[0];
#pragma unroll
  for (int i = 1; i < 4; ++i) smerge_s(m, lv, rm[i], rl[i]);
  float pg = sigmoidf(pgsum[b]);
  float scale = pg / lv;
  const int base = c * 5000;
  const int len = (c == 9) ? 5050 : 5000;
  const unsigned short* lr = logitsb + (size_t)b * V + base;
  for (int i = t; i < len; i += 256)
    sp_[i] = (i < 5000) ? scale * __expf(bf16s_to_f(lr[i]) - m) + 1e-12f : 1e-12f;
  __syncthreads();
  float wgt = 1.f - pg;
  for (int s = t; s < S; s += 256) {
    int idx = extv[b * S + s] - base;
    if ((unsigned)idx < (unsigned)len) atomicAdd(&sp_[idx], wgt * alphasT[b * S + s]);
  }
  __syncthreads();
  float* orow = out + (size_t)b * VEXT + base;
  for (int i = t; i < len; i += 256) orow[i] = __logf(sp_[i]);
}
}  // namespace

extern "C" void kernel_launch(void* const* d_in, const int* in_sizes, int n_in,
                              void* d_out, int out_size, void* d_ws, size_t ws_size,
                              hipStream_t stream) {
  const int*   tok   = (const int*)d_in[0];
  const float* ench  = (const float*)d_in[1];
  const float* pk    = (const float*)d_in[2];
  const float* prevh = (const float*)d_in[4];
  const int*   extv  = (const int*)d_in[5];
  const float* emb   = (const float*)d_in[7];
  const float* Wq    = (const float*)d_in[8];
  const float* We    = (const float*)d_in[9];
  const float* Wih   = (const float*)d_in[10];
  const float* Whh   = (const float*)d_in[11];
  const float* bih   = (const float*)d_in[12];
  const float* bhh   = (const float*)d_in[13];
  const float* linW  = (const float*)d_in[14];
  const float* linb  = (const float*)d_in[15];
  const float* pgW   = (const float*)d_in[16];
  const float* pgb   = (const float*)d_in[17];
  const float* outW  = (const float*)d_in[18];
  const float* outb  = (const float*)d_in[19];

  float* out = (float*)d_out;
  float* ws = (float*)d_ws;

  float* qpart   = ws;                   // 4*64*512 = 131072
  float* scoresT = qpart + 131072;       // 32000
  float* alphasT = scoresT + 32000;      // 32000
  float* cc      = alphasT + 32000;      // 64*1792 = 114688
  float* gip     = cc + 114688;          // 5*64*1536 = 491520
  float* ghp     = gip + 491520;         // 2*64*1536 = 196608
  float* linpart = ghp + 196608;         // 5*64*512 = 163840
  float* pgsum   = linpart + 163840;     // 64
  float* pm      = pgsum + 64;           // 25024
  float* pl      = pm + 25024;           // 25024
  unsigned short* logitsb = (unsigned short*)(pl + 25024);  // 64*50000 ushorts
  short* lh      = (short*)(logitsb + (size_t)B * V);       // 32768 shorts
  float* hout    = out + (size_t)B * VEXT;

  k_head<<<dim3(36), dim3(256), 0, stream>>>(prevh, Wq, tok, emb, qpart, cc);
  k_scores<<<dim3(8000), dim3(256), 0, stream>>>(qpart, pk, We, scoresT);
  k_ctx<<<dim3(512), dim3(256), 0, stream>>>(scoresT, ench, cc, alphasT);
  k_gemm_big<<<dim3(208), dim3(256), 0, stream>>>(cc, prevh, Wih, Whh, linW, gip,
                                                  linpart, ghp);
  k_gates<<<dim3(B), dim3(512), 0, stream>>>(gip, ghp, bih, bhh, prevh, pgW, pgb, cc,
                                             hout, pgsum);
  k_linfin<<<dim3(8), dim3(256), 0, stream>>>(cc, linW, linpart, linb, lh);
  k_gemm_logits<<<dim3(NLB), dim3(512), 0, stream>>>(lh, outW, outb, logitsb, pm, pl);
  k_final<<<dim3(B, 10), dim3(256), 0, stream>>>(logitsb, pm, pl, pgsum, extv, alphasT, out);
}

// Round 8
// 144.823 us; speedup vs baseline: 1.0635x; 1.0635x over previous
//
#include <hip/hip_runtime.h>
#include <hip/hip_bf16.h>
#include <math.h>

namespace {
constexpr int V = 50000, E = 256, H = 512, S = 500, B = 64, OOVN = 50;
constexpr int VEXT = V + OOVN;   // 50050
constexpr int CCAT = E + 3 * H;  // 1792  (embed | h_new | context)
constexpr int G3 = 3 * H;        // 1536
constexpr int NLB = 391;         // logits blocks (3128 waves, 3125 active)

typedef __attribute__((ext_vector_type(8))) short short8;
typedef __attribute__((ext_vector_type(4))) float f32x4;

__device__ __forceinline__ float wsum(float v) {
#pragma unroll
  for (int off = 32; off > 0; off >>= 1) v += __shfl_xor(v, off, 64);
  return v;
}
__device__ __forceinline__ float sigmoidf(float x) { return 1.f / (1.f + __expf(-x)); }
__device__ __forceinline__ float fast_tanh(float x) {
  x = fminf(fmaxf(x, -15.f), 15.f);
  float e = __expf(2.f * x);
  return __fdividef(e - 1.f, e + 1.f);
}
__device__ __forceinline__ void smerge_s(float& m, float& l, float om, float ol) {
  float nm = fmaxf(m, om);
  if (nm == -INFINITY) { m = nm; return; }
  l = l * __expf(m - nm) + ol * __expf(om - nm);
  m = nm;
}
__device__ __forceinline__ short bf16_rn_s(float f) {
  __hip_bfloat16 h = __float2bfloat16(f);
  return __builtin_bit_cast(short, h);
}
__device__ __forceinline__ float bf16s_to_f(unsigned short u) {
  return __uint_as_float(((unsigned)u) << 16);
}
__device__ __forceinline__ void hilo8(float4 a, float4 b, short8& hi, short8& lo) {
  float f[8] = {a.x, a.y, a.z, a.w, b.x, b.y, b.z, b.w};
#pragma unroll
  for (int i = 0; i < 8; ++i) {
    unsigned u = __float_as_uint(f[i]);
    hi[i] = (short)(u >> 16);
    lo[i] = bf16_rn_s(f[i] - __uint_as_float(u & 0xffff0000u));
  }
}

// ---- MFMA core, fp32 X with in-register hi/lo split; wave does C[0:64][n0:n0+16] ----
template <int KSTEPS>
__device__ __forceinline__ void gemm_core_f32(const float* __restrict__ X, int ldx,
                                              int xk0, const float* __restrict__ W,
                                              int ldw, int wk0, int n0, f32x4 acc[4]) {
  const int l = threadIdx.x & 63;
  const int r16 = l & 15, q16 = l >> 4;
#pragma unroll
  for (int t = 0; t < 4; ++t) acc[t] = (f32x4){0.f, 0.f, 0.f, 0.f};
  const float* wp = W + (size_t)(n0 + r16) * ldw + wk0 + q16 * 8;
  const float* xp[4];
#pragma unroll
  for (int t = 0; t < 4; ++t) xp[t] = X + (size_t)(t * 16 + r16) * ldx + xk0 + q16 * 8;
#pragma unroll
  for (int ks = 0; ks < KSTEPS; ++ks) {
    const int ko = ks * 32;
    float4 w0 = *reinterpret_cast<const float4*>(wp + ko);
    float4 w1 = *reinterpret_cast<const float4*>(wp + ko + 4);
    short8 whi, wlo;
    hilo8(w0, w1, whi, wlo);
#pragma unroll
    for (int t = 0; t < 4; ++t) {
      float4 x0 = *reinterpret_cast<const float4*>(xp[t] + ko);
      float4 x1 = *reinterpret_cast<const float4*>(xp[t] + ko + 4);
      short8 ah, al;
      hilo8(x0, x1, ah, al);
      acc[t] = __builtin_amdgcn_mfma_f32_16x16x32_bf16(ah, whi, acc[t], 0, 0, 0);
      acc[t] = __builtin_amdgcn_mfma_f32_16x16x32_bf16(al, whi, acc[t], 0, 0, 0);
      acc[t] = __builtin_amdgcn_mfma_f32_16x16x32_bf16(ah, wlo, acc[t], 0, 0, 0);
    }
  }
}
template <int KSTEPS>
__device__ __forceinline__ void gemm_store_f32(const float* X, int ldx, int xk0,
                                               const float* W, int ldw, int wk0, int n0,
                                               float* C, int ldc) {
  f32x4 acc[4];
  gemm_core_f32<KSTEPS>(X, ldx, xk0, W, ldw, wk0, n0, acc);
  const int l = threadIdx.x & 63;
  const int r16 = l & 15, q16 = l >> 4;
#pragma unroll
  for (int t = 0; t < 4; ++t)
#pragma unroll
    for (int r = 0; r < 4; ++r) {
      int row = t * 16 + q16 * 4 + r;
      C[(size_t)row * ldc + n0 + r16] = acc[t][r];
    }
}

// ---- head: q gemm (4 K-chunks) + gh gemm (2 K-chunks) + embed gather ----
__global__ void __launch_bounds__(256) k_head(const float* __restrict__ prevh,
                                              const float* __restrict__ Wq,
                                              const float* __restrict__ Whh,
                                              const int* __restrict__ tok,
                                              const float* __restrict__ emb,
                                              float* __restrict__ qpart,
                                              float* __restrict__ ghp,
                                              float* __restrict__ cc) {
  int gw = blockIdx.x * 4 + (threadIdx.x >> 6);  // 0..335
  if (gw < 128) {
    int c = gw >> 5, nt = gw & 31;
    gemm_store_f32<4>(prevh, H, c * 128, Wq, H, c * 128, nt * 16,
                      qpart + (size_t)c * 64 * H, H);
  } else if (gw < 320) {
    int w2 = gw - 128;
    int c = w2 / 96, nt = w2 % 96;
    gemm_store_f32<8>(prevh, H, c * 256, Whh, H, c * 256, nt * 16,
                      ghp + (size_t)c * 64 * G3, G3);
  } else {
    int idx = (gw - 320) * 64 + (threadIdx.x & 63);  // 0..1023
    for (int i = idx; i < B * E; i += 1024) {
      int b = i >> 8, e = i & 255;
      cc[b * CCAT + e] = emb[(size_t)tok[b] * E + e];
    }
  }
}

// ---- fused attention: scores + local softmax + partial context per (b, s-chunk) ----
__global__ void __launch_bounds__(256) k_attn(
    const float* __restrict__ qpart, const float* __restrict__ pk,
    const float* __restrict__ We, const float* __restrict__ ench,
    float* __restrict__ scoresT, float* __restrict__ ctxp, float* __restrict__ pml) {
  int x = blockIdx.x;  // 512 = b*8 + ch
  int b = x >> 3, ch = x & 7;
  int cnt = (ch < 4) ? 63 : 62;
  int s0 = ch * 62 + ((ch < 4) ? ch : 4);
  int t = threadIdx.x, w = t >> 6, lane = t & 63;
  __shared__ float es[64];
  // per-lane q (sum of 4 qpart chunks) and We held in registers
  float4 q0 = {0.f, 0.f, 0.f, 0.f}, q1 = {0.f, 0.f, 0.f, 0.f};
#pragma unroll
  for (int c = 0; c < 4; ++c) {
    const float* qb = qpart + ((size_t)c * 64 + b) * H + lane * 8;
    float4 a0 = *reinterpret_cast<const float4*>(qb);
    float4 a1 = *reinterpret_cast<const float4*>(qb + 4);
    q0.x += a0.x; q0.y += a0.y; q0.z += a0.z; q0.w += a0.w;
    q1.x += a1.x; q1.y += a1.y; q1.z += a1.z; q1.w += a1.w;
  }
  float4 e0 = *reinterpret_cast<const float4*>(We + lane * 8);
  float4 e1 = *reinterpret_cast<const float4*>(We + lane * 8 + 4);
  // phase 1: scores for this chunk (waves round-robin over s)
#pragma unroll 2
  for (int j = w; j < cnt; j += 4) {
    int s = s0 + j;
    const float* kr = pk + ((size_t)s * B + b) * H + lane * 8;
    float4 k0 = *reinterpret_cast<const float4*>(kr);
    float4 k1 = *reinterpret_cast<const float4*>(kr + 4);
    float part = fast_tanh(q0.x + k0.x) * e0.x + fast_tanh(q0.y + k0.y) * e0.y +
                 fast_tanh(q0.z + k0.z) * e0.z + fast_tanh(q0.w + k0.w) * e0.w +
                 fast_tanh(q1.x + k1.x) * e1.x + fast_tanh(q1.y + k1.y) * e1.y +
                 fast_tanh(q1.z + k1.z) * e1.z + fast_tanh(q1.w + k1.w) * e1.w;
    part = wsum(part);
    if (lane == 0) { es[j] = part; scoresT[b * S + s] = part; }
  }
  __syncthreads();
  // phase 2: local (m, l) and unnormalized weights (wave 0 only)
  if (w == 0) {
    float v = (lane < cnt) ? es[lane] : -INFINITY;
    float m = v;
#pragma unroll
    for (int off = 32; off > 0; off >>= 1) m = fmaxf(m, __shfl_xor(m, off, 64));
    float e = (lane < cnt) ? __expf(v - m) : 0.f;
    float l = wsum(e);
    es[lane] = e;  // wave-synchronous: reads above already done
    if (lane == 0) { pml[2 * x] = m; pml[2 * x + 1] = l; }
  }
  __syncthreads();
  // phase 3: partial context over this chunk (thread t owns cols 4t..4t+3)
  float4 acc = {0.f, 0.f, 0.f, 0.f};
  const float* eb = ench + ((size_t)s0 * B + b) * 1024 + t * 4;
#pragma unroll 4
  for (int j = 0; j < cnt; ++j) {
    float wgt = es[j];
    float4 v = *reinterpret_cast<const float4*>(eb + (size_t)j * (B * 1024));
    acc.x += wgt * v.x; acc.y += wgt * v.y; acc.z += wgt * v.z; acc.w += wgt * v.w;
  }
  *reinterpret_cast<float4*>(ctxp + (size_t)x * 1024 + t * 4) = acc;
}

// ---- combine chunk partials: cc ctx region (plain stores) + normalized alphasT ----
__global__ void __launch_bounds__(256) k_attn2(
    const float* __restrict__ ctxp, const float* __restrict__ pml,
    const float* __restrict__ scoresT, float* __restrict__ cc,
    float* __restrict__ alphasT) {
  int b = blockIdx.x, t = threadIdx.x;
  float m = -INFINITY;
#pragma unroll
  for (int ch = 0; ch < 8; ++ch) m = fmaxf(m, pml[2 * (b * 8 + ch)]);
  float L = 0.f;
  float sc[8];
#pragma unroll
  for (int ch = 0; ch < 8; ++ch) {
    float sf = __expf(pml[2 * (b * 8 + ch)] - m);
    sc[ch] = sf;
    L += pml[2 * (b * 8 + ch) + 1] * sf;
  }
  float inv = 1.f / L;
  float4 acc = {0.f, 0.f, 0.f, 0.f};
#pragma unroll
  for (int ch = 0; ch < 8; ++ch) {
    float4 v = *reinterpret_cast<const float4*>(ctxp + (size_t)(b * 8 + ch) * 1024 + t * 4);
    acc.x += sc[ch] * v.x; acc.y += sc[ch] * v.y;
    acc.z += sc[ch] * v.z; acc.w += sc[ch] * v.w;
  }
  acc.x *= inv; acc.y *= inv; acc.z *= inv; acc.w *= inv;
  *reinterpret_cast<float4*>(cc + b * CCAT + 768 + t * 4) = acc;
  for (int s = t; s < S; s += 256)
    alphasT[b * S + s] = __expf(scoresT[b * S + s] - m) * inv;
}

// ---- big fused gemm: gi (5 chunks) + lin embed/ctx chunks (5) ----
__global__ void __launch_bounds__(256) k_gemm_big(const float* __restrict__ cc,
                                                  const float* __restrict__ Wih,
                                                  const float* __restrict__ linW,
                                                  float* __restrict__ gip,
                                                  float* __restrict__ linpart) {
  int w = blockIdx.x * 4 + (threadIdx.x >> 6);  // 0..639
  if (w < 480) {
    int c = w / 96, nt = w % 96;
    int xk0 = (c == 0) ? 0 : 768 + (c - 1) * 256;
    gemm_store_f32<8>(cc, CCAT, xk0, Wih, 1280, c * 256, nt * 16,
                      gip + (size_t)c * 64 * G3, G3);
  } else {
    int w2 = w - 480;
    int c = w2 >> 5, nt = w2 & 31;
    int k0 = (c == 0) ? 0 : 768 + (c - 1) * 256;
    gemm_store_f32<8>(cc, CCAT, k0, linW, CCAT, k0, nt * 16,
                      linpart + (size_t)c * 64 * H, H);
  }
}

// ---- GRU gates + p_gen: block per b, 512 threads ----
__global__ void k_gates(const float* __restrict__ gip, const float* __restrict__ ghp,
                        const float* __restrict__ bih, const float* __restrict__ bhh,
                        const float* __restrict__ prevh, const float* __restrict__ pgW,
                        const float* __restrict__ pgb, float* __restrict__ cc,
                        float* __restrict__ hout, float* __restrict__ pgsum) {
  int b = blockIdx.x, j = threadIdx.x;  // 64 x 512
  float ir = bih[j], iz = bih[512 + j], in_ = bih[1024 + j];
#pragma unroll
  for (int c = 0; c < 5; ++c) {
    const float* g = gip + (size_t)c * 64 * G3 + b * G3;
    ir += g[j]; iz += g[512 + j]; in_ += g[1024 + j];
  }
  float hr = bhh[j], hz = bhh[512 + j], hn = bhh[1024 + j];
#pragma unroll
  for (int c = 0; c < 2; ++c) {
    const float* g = ghp + (size_t)c * 64 * G3 + b * G3;
    hr += g[j]; hz += g[512 + j]; hn += g[1024 + j];
  }
  float r = sigmoidf(ir + hr);
  float z = sigmoidf(iz + hz);
  float n = fast_tanh(in_ + r * hn);
  float h = prevh[b * H + j];
  float hnew = (1.f - z) * n + z * h;
  hout[b * H + j] = hnew;
  cc[b * CCAT + E + j] = hnew;
  float acc = hnew * pgW[E + j];
  acc += cc[b * CCAT + 768 + j] * pgW[768 + j];
  acc += cc[b * CCAT + 1280 + j] * pgW[1280 + j];
  if (j < 256) acc += cc[b * CCAT + j] * pgW[j];
  acc = wsum(acc);
  __shared__ float sl[8];
  int w = j >> 6, lane = j & 63;
  if (lane == 0) sl[w] = acc;
  __syncthreads();
  if (j == 0) {
    float tot = pgb[0];
#pragma unroll
    for (int i = 0; i < 8; ++i) tot += sl[i];
    pgsum[b] = tot;
  }
}

// ---- lin h-part gemm (K=512) + sum 5 partials + bias -> lh bf16 ----
__global__ void __launch_bounds__(256) k_linfin(const float* __restrict__ cc,
                                                const float* __restrict__ linW,
                                                const float* __restrict__ linpart,
                                                const float* __restrict__ linb,
                                                short* __restrict__ lh) {
  int w = blockIdx.x * 4 + (threadIdx.x >> 6);  // 0..31
  f32x4 acc[4];
  gemm_core_f32<16>(cc, CCAT, 256, linW, CCAT, 256, w * 16, acc);
  const int l = threadIdx.x & 63;
  const int r16 = l & 15, q16 = l >> 4;
  int col = w * 16 + r16;
  float bv = linb[col];
#pragma unroll
  for (int t = 0; t < 4; ++t)
#pragma unroll
    for (int r = 0; r < 4; ++r) {
      int row = t * 16 + q16 * 4 + r;
      float v = acc[t][r] + bv;
#pragma unroll
      for (int c = 0; c < 5; ++c) v += linpart[(size_t)c * 64 * H + row * H + col];
      lh[row * H + col] = bf16_rn_s(v);
    }
}

// ---- logits gemm (bf16 out) + per-block online-softmax partials ----
__global__ void __launch_bounds__(512) k_gemm_logits(
    const short* __restrict__ lh, const float* __restrict__ outW,
    const float* __restrict__ outb, unsigned short* __restrict__ logitsb,
    float* __restrict__ pm, float* __restrict__ pl) {
  __shared__ __align__(16) short xs[64 * 512];
  __shared__ float pml[8][64][2];
  char* xb = reinterpret_cast<char*>(xs);
  int tid = threadIdx.x;
#pragma unroll
  for (int k = 0; k < 8; ++k) {
    int m = k * 512 + tid;
    int row = m >> 6;
    short8 v = *reinterpret_cast<const short8*>(lh + (size_t)m * 8);
    int byte = (m * 16) ^ ((row & 7) << 4);
    *reinterpret_cast<short8*>(xb + byte) = v;
  }
  __syncthreads();
  const int l = tid & 63;
  const int r16 = l & 15, q16 = l >> 4;
  const int wid = tid >> 6;
  const int waveId = blockIdx.x * 8 + wid;
  const bool active = waveId < V / 16;
  if (active) {
    const int n0 = waveId * 16;
    f32x4 acc[4];
#pragma unroll
    for (int t = 0; t < 4; ++t) acc[t] = (f32x4){0.f, 0.f, 0.f, 0.f};
    const float* wp = outW + (size_t)(n0 + r16) * H + q16 * 8;
    int arow[4], aswz[4];
#pragma unroll
    for (int t = 0; t < 4; ++t) {
      int row = t * 16 + r16;
      arow[t] = row * 1024 + q16 * 16;
      aswz[t] = (row & 7) << 4;
    }
#pragma unroll
    for (int ks = 0; ks < 16; ++ks) {
      float4 w0 = *reinterpret_cast<const float4*>(wp + ks * 32);
      float4 w1 = *reinterpret_cast<const float4*>(wp + ks * 32 + 4);
      short8 wh;
      wh[0] = bf16_rn_s(w0.x); wh[1] = bf16_rn_s(w0.y);
      wh[2] = bf16_rn_s(w0.z); wh[3] = bf16_rn_s(w0.w);
      wh[4] = bf16_rn_s(w1.x); wh[5] = bf16_rn_s(w1.y);
      wh[6] = bf16_rn_s(w1.z); wh[7] = bf16_rn_s(w1.w);
#pragma unroll
      for (int t = 0; t < 4; ++t) {
        short8 a = *reinterpret_cast<const short8*>(xb + ((arow[t] + ks * 64) ^ aswz[t]));
        acc[t] = __builtin_amdgcn_mfma_f32_16x16x32_bf16(a, wh, acc[t], 0, 0, 0);
      }
    }
    float bv = outb[n0 + r16];
#pragma unroll
    for (int t = 0; t < 4; ++t)
#pragma unroll
      for (int r = 0; r < 4; ++r) {
        float y = acc[t][r] + bv;
        int row = t * 16 + q16 * 4 + r;
        logitsb[(size_t)row * V + n0 + r16] = (unsigned short)bf16_rn_s(y);
        float m = y;
#pragma unroll
        for (int off = 8; off > 0; off >>= 1) m = fmaxf(m, __shfl_xor(m, off, 64));
        float e = __expf(y - m);
#pragma unroll
        for (int off = 8; off > 0; off >>= 1) e += __shfl_xor(e, off, 64);
        if (r16 == 0) { pml[wid][row][0] = m; pml[wid][row][1] = e; }
      }
  } else if (r16 == 0) {
#pragma unroll
    for (int t = 0; t < 4; ++t)
#pragma unroll
      for (int r = 0; r < 4; ++r) {
        int row = t * 16 + q16 * 4 + r;
        pml[wid][row][0] = -INFINITY;
        pml[wid][row][1] = 0.f;
      }
  }
  __syncthreads();
  if (tid < 64) {
    float m = pml[0][tid][0], lv = pml[0][tid][1];
#pragma unroll
    for (int i = 1; i < 8; ++i) smerge_s(m, lv, pml[i][tid][0], pml[i][tid][1]);
    pm[blockIdx.x * 64 + tid] = m;
    pl[blockIdx.x * 64 + tid] = lv;
  }
}

// ---- final: reduce partials -> probs in LDS -> scatter (LDS atomics) -> log -> out ----
__global__ void k_final(const unsigned short* __restrict__ logitsb,
                        const float* __restrict__ pm, const float* __restrict__ pl,
                        const float* __restrict__ pgsum, const int* __restrict__ extv,
                        const float* __restrict__ alphasT, float* __restrict__ out) {
  int b = blockIdx.x, c = blockIdx.y, t = threadIdx.x;  // 64 x 10, 256 thr
  __shared__ float sp_[5056];
  __shared__ float rm[4], rl[4];
  float m = -INFINITY, lv = 0.f;
  for (int i = t; i < NLB; i += 256) smerge_s(m, lv, pm[i * 64 + b], pl[i * 64 + b]);
#pragma unroll
  for (int off = 32; off > 0; off >>= 1) {
    float om = __shfl_xor(m, off, 64), ol = __shfl_xor(lv, off, 64);
    smerge_s(m, lv, om, ol);
  }
  int w = t >> 6, lane = t & 63;
  if (lane == 0) { rm[w] = m; rl[w] = lv; }
  __syncthreads();
  m = rm[0]; lv = rl[0];
#pragma unroll
  for (int i = 1; i < 4; ++i) smerge_s(m, lv, rm[i], rl[i]);
  float pg = sigmoidf(pgsum[b]);
  float scale = pg / lv;
  const int base = c * 5000;
  const int len = (c == 9) ? 5050 : 5000;
  const unsigned short* lr = logitsb + (size_t)b * V + base;
  for (int i = t; i < len; i += 256)
    sp_[i] = (i < 5000) ? scale * __expf(bf16s_to_f(lr[i]) - m) + 1e-12f : 1e-12f;
  __syncthreads();
  float wgt = 1.f - pg;
  for (int s = t; s < S; s += 256) {
    int idx = extv[b * S + s] - base;
    if ((unsigned)idx < (unsigned)len) atomicAdd(&sp_[idx], wgt * alphasT[b * S + s]);
  }
  __syncthreads();
  float* orow = out + (size_t)b * VEXT + base;
  for (int i = t; i < len; i += 256) orow[i] = __logf(sp_[i]);
}
}  // namespace

extern "C" void kernel_launch(void* const* d_in, const int* in_sizes, int n_in,
                              void* d_out, int out_size, void* d_ws, size_t ws_size,
                              hipStream_t stream) {
  const int*   tok   = (const int*)d_in[0];
  const float* ench  = (const float*)d_in[1];
  const float* pk    = (const float*)d_in[2];
  const float* prevh = (const float*)d_in[4];
  const int*   extv  = (const int*)d_in[5];
  const float* emb   = (const float*)d_in[7];
  const float* Wq    = (const float*)d_in[8];
  const float* We    = (const float*)d_in[9];
  const float* Wih   = (const float*)d_in[10];
  const float* Whh   = (const float*)d_in[11];
  const float* bih   = (const float*)d_in[12];
  const float* bhh   = (const float*)d_in[13];
  const float* linW  = (const float*)d_in[14];
  const float* linb  = (const float*)d_in[15];
  const float* pgW   = (const float*)d_in[16];
  const float* pgb   = (const float*)d_in[17];
  const float* outW  = (const float*)d_in[18];
  const float* outb  = (const float*)d_in[19];

  float* out = (float*)d_out;
  float* ws = (float*)d_ws;

  float* qpart   = ws;                   // 4*64*512 = 131072
  float* scoresT = qpart + 131072;       // 32000
  float* alphasT = scoresT + 32000;      // 32000
  float* ctxp    = alphasT + 32000;      // 8*64*1024 = 524288
  float* pml     = ctxp + 524288;        // 1024
  float* cc      = pml + 1024;           // 64*1792 = 114688
  float* gip     = cc + 114688;          // 5*64*1536 = 491520
  float* ghp     = gip + 491520;         // 2*64*1536 = 196608
  float* linpart = ghp + 196608;         // 5*64*512 = 163840
  float* pgsum   = linpart + 163840;     // 64
  float* pm      = pgsum + 64;           // 25024
  float* pl      = pm + 25024;           // 25024
  unsigned short* logitsb = (unsigned short*)(pl + 25024);  // 64*50000 ushorts
  short* lh      = (short*)(logitsb + (size_t)B * V);       // 32768 shorts
  float* hout    = out + (size_t)B * VEXT;

  k_head<<<dim3(84), dim3(256), 0, stream>>>(prevh, Wq, Whh, tok, emb, qpart, ghp, cc);
  k_attn<<<dim3(512), dim3(256), 0, stream>>>(qpart, pk, We, ench, scoresT, ctxp, pml);
  k_attn2<<<dim3(B), dim3(256), 0, stream>>>(ctxp, pml, scoresT, cc, alphasT);
  k_gemm_big<<<dim3(160), dim3(256), 0, stream>>>(cc, Wih, linW, gip, linpart);
  k_gates<<<dim3(B), dim3(512), 0, stream>>>(gip, ghp, bih, bhh, prevh, pgW, pgb, cc,
                                             hout, pgsum);
  k_linfin<<<dim3(8), dim3(256), 0, stream>>>(cc, linW, linpart, linb, lh);
  k_gemm_logits<<<dim3(NLB), dim3(512), 0, stream>>>(lh, outW, outb, logitsb, pm, pl);
  k_final<<<dim3(B, 10), dim3(256), 0, stream>>>(logitsb, pm, pl, pgsum, extv, alphasT, out);
}